// Round 1
// 996.316 us; speedup vs baseline: 1.0450x; 1.0450x over previous
//
#include <hip/hip_runtime.h>

typedef float floatx4 __attribute__((ext_vector_type(4)));

#define F8_MAX 448.0f
#define BM 256
#define BN 256
#define BK 64
#define TILE_A (BM * BK) /* 16 KiB */
#define TILE_B (BN * BK) /* 16 KiB */

// ---------------------------------------------------------------------------
// amax reduction, x and w merged into one launch (blocks [0,nbx) -> x, rest -> w).
// float4 grid-stride -> wave shuffle max -> block max -> atomicMax on uint bits.
// ---------------------------------------------------------------------------
__global__ void amax2_kernel(const float* __restrict__ x, int n4x,
                             const float* __restrict__ w, int n4w,
                             unsigned* __restrict__ out, int nbx) {
  const bool isX = (int)blockIdx.x < nbx;
  const float4* __restrict__ src = (const float4*)(isX ? x : w);
  const int n4 = isX ? n4x : n4w;
  const int bid = isX ? (int)blockIdx.x : (int)blockIdx.x - nbx;
  const int nb = isX ? nbx : (int)gridDim.x - nbx;
  float m = 0.0f;
  const int stride = nb * blockDim.x;
#pragma unroll 4
  for (int i = bid * blockDim.x + threadIdx.x; i < n4; i += stride) {
    float4 v = src[i];
    m = fmaxf(m, fmaxf(fmaxf(fabsf(v.x), fabsf(v.y)),
                       fmaxf(fabsf(v.z), fabsf(v.w))));
  }
  for (int off = 32; off > 0; off >>= 1)
    m = fmaxf(m, __shfl_down(m, off, 64));
  __shared__ float wmax[4];
  int wave = threadIdx.x >> 6;
  if ((threadIdx.x & 63) == 0) wmax[wave] = m;
  __syncthreads();
  if (threadIdx.x == 0) {
    float bm = fmaxf(fmaxf(wmax[0], wmax[1]), fmaxf(wmax[2], wmax[3]));
    atomicMax(out + (isX ? 0 : 1), __float_as_uint(bm));
  }
}

// ---------------------------------------------------------------------------
// Quantize fp32 -> fp8 e4m3, x and w merged. Fully coalesced: 16B/lane load,
// 4B/lane store (prev version had 32B-stride lane pattern).
// Math matches jnp bit-exact: scale = amax/448 (fp32 div); inv = 1.0/scale;
// clip then RNE convert (v_cvt_pk_fp8_f32 is RNE; pre-clamp so no overflow).
// ---------------------------------------------------------------------------
__global__ void quant2_kernel(const float* __restrict__ x,
                              unsigned char* __restrict__ xq, int n4x,
                              const float* __restrict__ w,
                              unsigned char* __restrict__ wq, int n4w,
                              const unsigned* __restrict__ amax_bits, int nbx) {
  const bool isX = (int)blockIdx.x < nbx;
  const float amax = __uint_as_float(amax_bits[isX ? 0 : 1]);
  const float scale = amax / F8_MAX;  // fp32 division, matches reference
  const float inv = 1.0f / scale;     // matches reference's 1.0/scale
  const float4* __restrict__ src = (const float4*)(isX ? x : w);
  unsigned* __restrict__ dst = (unsigned*)(isX ? xq : wq);
  const int n4 = isX ? n4x : n4w;
  const int bid = isX ? (int)blockIdx.x : (int)blockIdx.x - nbx;
  const int nb = isX ? nbx : (int)gridDim.x - nbx;
  const int stride = nb * blockDim.x;
#pragma unroll 2
  for (int i = bid * blockDim.x + threadIdx.x; i < n4; i += stride) {
    float4 v = src[i];
    float c0 = fminf(fmaxf(v.x * inv, -F8_MAX), F8_MAX);
    float c1 = fminf(fmaxf(v.y * inv, -F8_MAX), F8_MAX);
    float c2 = fminf(fmaxf(v.z * inv, -F8_MAX), F8_MAX);
    float c3 = fminf(fmaxf(v.w * inv, -F8_MAX), F8_MAX);
    int p = __builtin_amdgcn_cvt_pk_fp8_f32(c0, c1, 0, false);
    p = __builtin_amdgcn_cvt_pk_fp8_f32(c2, c3, p, true);
    dst[i] = (unsigned)p;
  }
}

// ---------------------------------------------------------------------------
// Async global->LDS, 16B per lane. HW dest = wave-uniform base + lane*16.
// ---------------------------------------------------------------------------
__device__ inline void async_copy16(const unsigned char* g, unsigned char* l) {
  __builtin_amdgcn_global_load_lds(
      (const __attribute__((address_space(1))) void*)g,
      (__attribute__((address_space(3))) void*)l, 16, 0, 0);
}

// ---------------------------------------------------------------------------
// FP8 GEMM, 256x256 tile, 8-phase counted-vmcnt schedule (T2+T3+T4+T5 port of
// the m201 bf16 template to fp8 e4m3).
//
// 512 threads = 8 waves (2M x 4N); per-wave output 128x64 = 8x4 frags of
// 16x16x32 fp8 MFMA; acc = 128 VGPR.
//
// LDS: 4-deep ring of K-tiles (tile t -> buf t&3), A and B each 4x16 KiB
// = 128 KiB total. Staging granularity: half-tile = 128 rows x 64 B = 8 KiB
// = exactly one global_load_lds per thread (16 B x 512). 4 stages per K-tile:
// A[h0], A[h1], B[h0], B[h1].
//
// Pipeline: during tile t's 4 phases we issue tile (t+2)'s 4 stages (1/phase)
// into buf (t+2)&3 (its previous reader, tile t-2, retired 2 tiles ago).
// End-of-tile wait = s_waitcnt vmcnt(4): the only loads allowed to remain
// outstanding are tile (t+2)'s 4 -- so tile (t+1)'s loads have landed, which
// is exactly what the next tile's ds_reads need. Loads stay in flight across
// barriers (never vmcnt(0) in steady state). Tail (no stage issued): vmcnt(0).
//
// LDS swizzle (rule #21, both-sides-or-neither): within each 64 B row, 16 B
// chunk slot c holds logical chunk c ^ ((row>>1)&3). Implemented by inverse-
// permuting each thread's GLOBAL source chunk (LDS dest of global_load_lds
// must stay linear) and XOR-ing the same term into the ds_read address.
// Fragment read (b64): lane (l16=row, quad=k-granule) for kslice s reads
// logical granule s*4+quad -> chunk j=s*2+(quad>>1), slot c=j^((l16>>1)&3),
// byte (quad&1)*8. Bank check: bankpair = (l16&1)<<3 | ((swl^q1)&3)<<1 | q0
// -> every bankpair hit by exactly 4 of 64 lanes = the uniform b64 floor
// (512 B / 128 B-per-clk); no excess conflict cycles.
//
// Phase p of tile t: (hh = p&1 selects mi-half, s = p>>1 selects kslice);
// B frags are read once per kslice (phases 0,2) and reused in phases 1,3.
// A/B use the same (quad,s)->k mapping, so the k-reduction pairs correctly.
// ---------------------------------------------------------------------------
__global__ void __launch_bounds__(512) gemm_fp8(
    const unsigned char* __restrict__ Xq, const unsigned char* __restrict__ Wq,
    const float* __restrict__ bias, const unsigned* __restrict__ scales,
    float* __restrict__ C, int M, int N, int K) {
  __shared__ __align__(16) unsigned char As[4 * TILE_A];  // 64 KiB
  __shared__ __align__(16) unsigned char Bs[4 * TILE_B];  // 64 KiB

  const int tid = threadIdx.x;
  const int wave = tid >> 6;
  const int lane = tid & 63;
  const int quad = lane >> 4;
  const int l16 = lane & 15;
  const int wm = wave >> 2;  // 0..1 : M half
  const int wn = wave & 3;   // 0..3 : N quarter

  const int baseM = blockIdx.y * BM;
  const int baseN = blockIdx.x * BN;

  floatx4 acc[8][4];
#pragma unroll
  for (int i = 0; i < 8; i++)
#pragma unroll
    for (int j = 0; j < 4; j++) acc[i][j] = {0.f, 0.f, 0.f, 0.f};

  // ---- staging addresses (source-swizzled, LDS-linear) ----
  // thread t covers LDS bytes [t*16, t*16+16) of a half-tile: row t>>2,
  // chunk slot t&3; slot must hold logical chunk (t&3) ^ f(row),
  // f(row) = (row>>1)&3 = (t>>3)&3.
  const int sr = tid >> 2;                      // 0..127
  const int sj = (tid & 3) ^ ((tid >> 3) & 3);  // swizzled global chunk
  const unsigned char* gA0 = Xq + (size_t)(baseM + sr) * K + sj * 16;
  const unsigned char* gA1 = gA0 + (size_t)128 * K;
  const unsigned char* gB0 = Wq + (size_t)(baseN + sr) * K + sj * 16;
  const unsigned char* gB1 = gB0 + (size_t)128 * K;
  const int stOff = wave * 1024;  // + lane*16 implicit in global_load_lds

  // ---- fragment read offsets ----
  const int swl = (l16 >> 1) & 3;
  const int q1 = quad >> 1, q0 = quad & 1;
  const int cs0 = ((q1 ^ swl) * 16) + q0 * 8;        // kslice 0
  const int cs1 = (((2 + q1) ^ swl) * 16) + q0 * 8;  // kslice 1
  const int aBase = (wm * 128 + l16) * BK;           // + mi*16*BK
  const int bBase = (wn * 64 + l16) * BK;            // + ni*16*BK

  const int nt = K / BK;

  // ---- prologue: stage tiles 0,1 (order A0,A1,B0,B1 per tile) ----
  async_copy16(gA0, As + stOff);
  async_copy16(gA1, As + 8192 + stOff);
  async_copy16(gB0, Bs + stOff);
  async_copy16(gB1, Bs + 8192 + stOff);
  if (nt > 1) {
    async_copy16(gA0 + BK, As + TILE_A + stOff);
    async_copy16(gA1 + BK, As + TILE_A + 8192 + stOff);
    async_copy16(gB0 + BK, Bs + TILE_B + stOff);
    async_copy16(gB1 + BK, Bs + TILE_B + 8192 + stOff);
    asm volatile("s_waitcnt vmcnt(4)" ::: "memory");  // tile0 resident
  } else {
    asm volatile("s_waitcnt vmcnt(0)" ::: "memory");
  }
  __builtin_amdgcn_s_barrier();

  long a[4], b[4];

#define PHASE(HH, CS, DOB, STAGE)                                              \
  {                                                                            \
    _Pragma("unroll") for (int mi = 0; mi < 4; ++mi) a[mi] =                   \
        *(const long*)(Ab + aBase + ((HH)*4 + mi) * 1024 + (CS));              \
    if (DOB) {                                                                 \
      _Pragma("unroll") for (int ni = 0; ni < 4; ++ni) b[ni] =                 \
          *(const long*)(Bb + bBase + ni * 1024 + (CS));                       \
    }                                                                          \
    STAGE                                                                      \
    __builtin_amdgcn_s_barrier();                                              \
    asm volatile("s_waitcnt lgkmcnt(0)" ::: "memory");                         \
    __builtin_amdgcn_s_setprio(1);                                             \
    _Pragma("unroll") for (int mi = 0; mi < 4; ++mi) {                         \
      _Pragma("unroll") for (int ni = 0; ni < 4; ++ni) acc[(HH)*4 + mi][ni] =  \
          __builtin_amdgcn_mfma_f32_16x16x32_fp8_fp8(                          \
              a[mi], b[ni], acc[(HH)*4 + mi][ni], 0, 0, 0);                    \
    }                                                                          \
    __builtin_amdgcn_s_setprio(0);                                             \
  }

#pragma unroll 1
  for (int t = 0; t < nt; ++t) {
    const unsigned char* Ab = As + (t & 3) * TILE_A;
    const unsigned char* Bb = Bs + (t & 3) * TILE_B;
    const bool stg = (t + 2 < nt);
    const int bo2a = ((t + 2) & 3) * TILE_A;
    const int bo2b = ((t + 2) & 3) * TILE_B;
    const size_t k2 = (size_t)(t + 2) * BK;

    PHASE(0, cs0, 1, { if (stg) async_copy16(gA0 + k2, As + bo2a + stOff); })
    __builtin_amdgcn_s_barrier();
    PHASE(1, cs0, 0, { if (stg) async_copy16(gA1 + k2, As + bo2a + 8192 + stOff); })
    __builtin_amdgcn_s_barrier();
    PHASE(0, cs1, 1, { if (stg) async_copy16(gB0 + k2, Bs + bo2b + stOff); })
    __builtin_amdgcn_s_barrier();
    PHASE(1, cs1, 0, { if (stg) async_copy16(gB1 + k2, Bs + bo2b + 8192 + stOff); })
    if (stg) {
      asm volatile("s_waitcnt vmcnt(4)" ::: "memory");  // next tile resident
    } else {
      asm volatile("s_waitcnt vmcnt(0)" ::: "memory");  // tail drain
    }
    __builtin_amdgcn_s_barrier();
  }
#undef PHASE

  // ---- epilogue: out = acc * (sx*sw) + bias[n] ----
  // C/D layout: col = lane&15, row = quad*4 + reg  [m89/m91 verified]
  const float s = (__uint_as_float(scales[0]) / F8_MAX) *
                  (__uint_as_float(scales[1]) / F8_MAX);
#pragma unroll
  for (int ni = 0; ni < 4; ni++) {
    const int gn = baseN + wn * 64 + ni * 16 + l16;
    const float bv = bias[gn];
#pragma unroll
    for (int mi = 0; mi < 8; mi++) {
      const int gm = baseM + wm * 128 + mi * 16 + quad * 4;
      float* outp = C + (size_t)gm * N + gn;
#pragma unroll
      for (int r = 0; r < 4; r++) outp[(size_t)r * N] = acc[mi][ni][r] * s + bv;
    }
  }
}

// ---------------------------------------------------------------------------
// Launcher. Workspace: ws[0..3] amax_x bits | ws[4..7] amax_w bits |
// ws+256: Xq (M*K fp8) | then Wq (N*K fp8).
// ---------------------------------------------------------------------------
extern "C" void kernel_launch(void* const* d_in, const int* in_sizes, int n_in,
                              void* d_out, int out_size, void* d_ws,
                              size_t ws_size, hipStream_t stream) {
  const float* x = (const float*)d_in[0];
  const float* w = (const float*)d_in[1];
  const float* bias = (const float*)d_in[2];
  float* out = (float*)d_out;

  const int N = in_sizes[2];      // 4096
  const int K = in_sizes[1] / N;  // 4096
  const int M = in_sizes[0] / K;  // 16384

  unsigned* scales = (unsigned*)d_ws;
  unsigned char* xq = (unsigned char*)d_ws + 256;
  unsigned char* wq = xq + (size_t)M * K;

  const int NBX = 4096;  // x:w block split 4:1 matches element ratio
  const int NBW = 1024;

  hipMemsetAsync(d_ws, 0, 256, stream);  // ws is re-poisoned every launch
  amax2_kernel<<<NBX + NBW, 256, 0, stream>>>(x, (M * K) / 4, w, (N * K) / 4,
                                              scales, NBX);
  quant2_kernel<<<NBX + NBW, 256, 0, stream>>>(x, xq, (M * K) / 4, w, wq,
                                               (N * K) / 4, scales, NBX);

  dim3 grid(N / BN, M / BM);
  gemm_fp8<<<grid, 512, 0, stream>>>(xq, wq, bias, scales, out, M, N, K);
}